// Round 1
// baseline (421.696 us; speedup 1.0000x reference)
//
#include <hip/hip_runtime.h>
#include <stdint.h>

#define M_ROWS 4096   // BATCH*SEQ
#define N_OUT  4096   // OUT_FEATURES
#define K_IN   4096   // IN_FEATURES
#define NNZ_N  1677722

typedef __attribute__((ext_vector_type(8))) short  bf16x8_t;  // 8 bf16 in 4 VGPRs
typedef __attribute__((ext_vector_type(4))) float  f32x4_t;

// ---------- fp32 -> bf16 (RNE) ----------
__device__ __forceinline__ unsigned short f2bf(float f) {
    union { float f; uint32_t u; } v; v.f = f;
    uint32_t u = v.u;
    u += 0x7FFFu + ((u >> 16) & 1u);   // round-to-nearest-even
    return (unsigned short)(u >> 16);
}

__global__ void convert_f32_bf16(const float4* __restrict__ src,
                                 ushort4* __restrict__ dst) {
    int i = blockIdx.x * blockDim.x + threadIdx.x;  // exact-size grid, no bounds check
    float4 v = src[i];
    ushort4 o;
    o.x = f2bf(v.x); o.y = f2bf(v.y); o.z = f2bf(v.z); o.w = f2bf(v.w);
    dst[i] = o;
}

// ---------- COO scatter-add into dense W_f32 [N_OUT][K_IN] ----------
__global__ void scatter_coo(const float* __restrict__ data,
                            const int* __restrict__ rows,
                            const int* __restrict__ cols,
                            float* __restrict__ W, int nnz) {
    int i = blockIdx.x * blockDim.x + threadIdx.x;
    if (i < nnz) {
        atomicAdd(&W[(size_t)rows[i] * K_IN + cols[i]], data[i]);
    }
}

// ---------- async global->LDS helper (width 16B) ----------
__device__ __forceinline__ void async_ld16(const void* g, void* lds_wave_base) {
    __builtin_amdgcn_global_load_lds(
        (const __attribute__((address_space(1))) uint32_t*)g,
        (__attribute__((address_space(3))) uint32_t*)lds_wave_base,
        16, 0, 0);
}

// ---------- C[M][N] = A[M][K] * B[N][K]^T, bf16 inputs, fp32 out ----------
// 128x128 block tile, BK=32, 256 threads = 4 waves (2x2 of 64x64 wave tiles),
// each wave: 4x4 grid of 16x16x32 MFMAs.
__global__ __launch_bounds__(256) void gemm_bt(const unsigned short* __restrict__ A,
                                               const unsigned short* __restrict__ B,
                                               float* __restrict__ C) {
    __shared__ __align__(16) unsigned short sA[128 * 32];
    __shared__ __align__(16) unsigned short sB[128 * 32];

    const int t    = threadIdx.x;
    const int wave = t >> 6;
    const int lane = t & 63;
    const int wr   = wave >> 1;       // wave row (0..1)
    const int wc   = wave & 1;        // wave col (0..1)
    const int m0   = blockIdx.y * 128;
    const int n0   = blockIdx.x * 128;

    // Staging geometry: tile = 128 rows x 32 cols bf16 = 8192 B = 512 x 16B loads
    //   = 2 instructions x 256 threads. linear id lin = it*256 + t,
    //   row = lin>>2, colElem = (lin&3)*8. LDS elem offset = lin*8.
    const int r0 = t >> 2;            // rows 0..63   (instr 0)
    const int r1 = 64 + (t >> 2);     // rows 64..127 (instr 1)
    const int c0 = (t & 3) * 8;       // element col within 32

    const unsigned short* gA0 = A + (size_t)(m0 + r0) * K_IN + c0;
    const unsigned short* gA1 = A + (size_t)(m0 + r1) * K_IN + c0;
    const unsigned short* gB0 = B + (size_t)(n0 + r0) * K_IN + c0;
    const unsigned short* gB1 = B + (size_t)(n0 + r1) * K_IN + c0;

    // wave-uniform LDS bases (HW adds lane*16B)
    unsigned short* lA0 = sA + wave * 512;          // instr0: elems [wave*512 ...]
    unsigned short* lA1 = sA + 2048 + wave * 512;   // instr1
    unsigned short* lB0 = sB + wave * 512;
    unsigned short* lB1 = sB + 2048 + wave * 512;

    const int lrow = lane & 15;           // m/n index within 16
    const int kgrp = (lane >> 4) * 8;     // k element group within 32

    f32x4_t acc[4][4];
#pragma unroll
    for (int im = 0; im < 4; ++im)
#pragma unroll
        for (int jn = 0; jn < 4; ++jn)
            acc[im][jn] = (f32x4_t){0.f, 0.f, 0.f, 0.f};

    const int sA_base = (wr * 64 + lrow) * 32 + kgrp;
    const int sB_base = (wc * 64 + lrow) * 32 + kgrp;

    for (int k0 = 0; k0 < K_IN; k0 += 32) {
        async_ld16(gA0 + k0, lA0);
        async_ld16(gA1 + k0, lA1);
        async_ld16(gB0 + k0, lB0);
        async_ld16(gB1 + k0, lB1);
        __syncthreads();   // drains vmcnt (global_load_lds) + barrier

        bf16x8_t af[4], bfr[4];
#pragma unroll
        for (int im = 0; im < 4; ++im)
            af[im] = *(const bf16x8_t*)(sA + sA_base + im * 16 * 32);
#pragma unroll
        for (int jn = 0; jn < 4; ++jn)
            bfr[jn] = *(const bf16x8_t*)(sB + sB_base + jn * 16 * 32);

#pragma unroll
        for (int im = 0; im < 4; ++im)
#pragma unroll
            for (int jn = 0; jn < 4; ++jn)
                acc[im][jn] = __builtin_amdgcn_mfma_f32_16x16x32_bf16(
                    af[im], bfr[jn], acc[im][jn], 0, 0, 0);

        __syncthreads();   // protect LDS before next stage
    }

    // Epilogue: C/D layout col = lane&15, row = (lane>>4)*4 + reg
    const int crow0 = m0 + wr * 64 + (lane >> 4) * 4;
    const int ccol0 = n0 + wc * 64 + lrow;
#pragma unroll
    for (int im = 0; im < 4; ++im)
#pragma unroll
        for (int jn = 0; jn < 4; ++jn)
#pragma unroll
            for (int r = 0; r < 4; ++r)
                C[(size_t)(crow0 + im * 16 + r) * N_OUT + ccol0 + jn * 16] =
                    acc[im][jn][r];
}

extern "C" void kernel_launch(void* const* d_in, const int* in_sizes, int n_in,
                              void* d_out, int out_size, void* d_ws, size_t ws_size,
                              hipStream_t stream) {
    const float* x    = (const float*)d_in[0];   // [2,2048,4096] fp32
    const float* data = (const float*)d_in[1];   // [NNZ]
    const int*   rows = (const int*)d_in[2];
    const int*   cols = (const int*)d_in[3];
    float*       out  = (float*)d_out;           // [2,2048,4096] fp32

    // workspace layout
    float*          W_f32  = (float*)d_ws;                               // 64 MiB
    unsigned short* W_bf16 = (unsigned short*)((char*)d_ws + (64u << 20)); // 32 MiB
    unsigned short* x_bf16 = (unsigned short*)((char*)d_ws + (96u << 20)); // 32 MiB

    // 1. zero dense W accumulator (ws is poisoned 0xAA before every call)
    hipMemsetAsync(W_f32, 0, (size_t)N_OUT * K_IN * sizeof(float), stream);

    // 2. scatter COO -> dense fp32
    scatter_coo<<<(NNZ_N + 255) / 256, 256, 0, stream>>>(data, rows, cols, W_f32, NNZ_N);

    // 3. convert W and x to bf16 (16,777,216 elems each; exact grids)
    const int conv_blocks = (N_OUT * K_IN) / (4 * 256);  // 16384
    convert_f32_bf16<<<conv_blocks, 256, 0, stream>>>((const float4*)W_f32, (ushort4*)W_bf16);
    convert_f32_bf16<<<conv_blocks, 256, 0, stream>>>((const float4*)x,     (ushort4*)x_bf16);

    // 4. y = x * W^T via bf16 MFMA GEMM
    dim3 grid(N_OUT / 128, M_ROWS / 128);  // 32 x 32
    gemm_bt<<<grid, 256, 0, stream>>>(x_bf16, W_bf16, out);
}

// Round 2
// 408.537 us; speedup vs baseline: 1.0322x; 1.0322x over previous
//
#include <hip/hip_runtime.h>
#include <stdint.h>

#define M_ROWS 4096   // BATCH*SEQ
#define N_OUT  4096   // OUT_FEATURES
#define K_IN   4096   // IN_FEATURES
#define NNZ_N  1677722

typedef __attribute__((ext_vector_type(8))) short  bf16x8_t;  // 8 bf16 in 4 VGPRs
typedef __attribute__((ext_vector_type(4))) float  f32x4_t;

// ---------- fp32 -> bf16 (RNE) ----------
__device__ __forceinline__ unsigned short f2bf(float f) {
    union { float f; uint32_t u; } v; v.f = f;
    uint32_t u = v.u;
    u += 0x7FFFu + ((u >> 16) & 1u);   // round-to-nearest-even
    return (unsigned short)(u >> 16);
}

// ---------- fused: zero W_f32 accumulator + convert x to bf16 ----------
// Both are independent streams over 4.19M float4 / thread-grid 16384x256.
__global__ void zero_and_convert_x(float4* __restrict__ Wz,
                                   const float4* __restrict__ x,
                                   ushort4* __restrict__ xo) {
    int i = blockIdx.x * blockDim.x + threadIdx.x;  // exact-size grid
    Wz[i] = (float4){0.f, 0.f, 0.f, 0.f};
    float4 v = x[i];
    ushort4 o;
    o.x = f2bf(v.x); o.y = f2bf(v.y); o.z = f2bf(v.z); o.w = f2bf(v.w);
    xo[i] = o;
}

__global__ void convert_f32_bf16(const float4* __restrict__ src,
                                 ushort4* __restrict__ dst) {
    int i = blockIdx.x * blockDim.x + threadIdx.x;
    float4 v = src[i];
    ushort4 o;
    o.x = f2bf(v.x); o.y = f2bf(v.y); o.z = f2bf(v.z); o.w = f2bf(v.w);
    dst[i] = o;
}

// ---------- COO scatter-add into dense W_f32 [N_OUT][K_IN] ----------
__global__ void scatter_coo(const float* __restrict__ data,
                            const int* __restrict__ rows,
                            const int* __restrict__ cols,
                            float* __restrict__ W, int nnz) {
    int i = blockIdx.x * blockDim.x + threadIdx.x;
    if (i < nnz) {
        atomicAdd(&W[(size_t)rows[i] * K_IN + cols[i]], data[i]);
    }
}

// ---------- async global->LDS helper (width 16B) ----------
__device__ __forceinline__ void async_ld16(const void* g, void* lds_wave_base) {
    __builtin_amdgcn_global_load_lds(
        (const __attribute__((address_space(1))) uint32_t*)g,
        (__attribute__((address_space(3))) uint32_t*)lds_wave_base,
        16, 0, 0);
}

// ---------- C[M][N] = A[M][K] * B[N][K]^T, bf16 inputs, fp32 out ----------
// 128x128 block tile, BK=32, 256 threads = 4 waves (2x2 of 64x64 wave tiles),
// each wave: 4x4 grid of 16x16x32 MFMAs.
//
// LDS layout is XOR-swizzled to kill read bank conflicts:
//   tile row = 64 B = 4 chunks of 16 B; chunk c of row r lives at physical
//   chunk position c ^ ((r>>1)&3). global_load_lds dst is wave-uniform
//   (lane*16B, no padding possible) but the global SOURCE address is per-lane,
//   so the swizzle is applied by permuting which chunk each lane fetches.
//   Frag reads then hit each 128B bank-row position 2x per 16-lane group
//   (2-way aliasing = free) instead of 8-way conflicts (was +4 cyc/ds_read).
__global__ __launch_bounds__(256) void gemm_bt(const unsigned short* __restrict__ A,
                                               const unsigned short* __restrict__ B,
                                               float* __restrict__ C) {
    __shared__ __align__(16) unsigned short sA[128 * 32];
    __shared__ __align__(16) unsigned short sB[128 * 32];

    const int t    = threadIdx.x;
    const int wave = t >> 6;
    const int lane = t & 63;
    const int wr   = wave >> 1;       // wave row (0..1)
    const int wc   = wave & 1;        // wave col (0..1)
    const int m0   = blockIdx.y * 128;
    const int n0   = blockIdx.x * 128;

    // Staging: tile = 128 rows x 32 k-elems bf16 = 8192 B = 512 x 16B chunks
    //   = 2 instructions x 256 threads. LDS chunk lin = it*256 + t holds
    //   global (row = lin>>2, chunk c_src = (lin&3) ^ ((row>>1)&3)).
    //   (row>>1)&3 == (t>>3)&3 for both instructions (i*64 doesn't touch bits 1-2).
    const int r0    = t >> 2;                         // rows 0..63   (instr 0)
    const int r1    = 64 + (t >> 2);                  // rows 64..127 (instr 1)
    const int c_src = ((t & 3) ^ ((t >> 3) & 3)) * 8; // swizzled source chunk (elems)

    const unsigned short* gA0 = A + (size_t)(m0 + r0) * K_IN + c_src;
    const unsigned short* gA1 = A + (size_t)(m0 + r1) * K_IN + c_src;
    const unsigned short* gB0 = B + (size_t)(n0 + r0) * K_IN + c_src;
    const unsigned short* gB1 = B + (size_t)(n0 + r1) * K_IN + c_src;

    // wave-uniform LDS bases (HW adds lane*16B)
    unsigned short* lA0 = sA + wave * 512;
    unsigned short* lA1 = sA + 2048 + wave * 512;
    unsigned short* lB0 = sB + wave * 512;
    unsigned short* lB1 = sB + 2048 + wave * 512;

    const int lrow = lane & 15;           // m/n index within 16
    // swizzled k-chunk for frag reads: physical chunk = (lane>>4) ^ ((lrow>>1)&3)
    // (row = base + lrow + im*16: im*16 / wr*64 don't touch row bits 1-2)
    const int kchunk = ((lane >> 4) ^ ((lrow >> 1) & 3)) * 8;

    f32x4_t acc[4][4];
#pragma unroll
    for (int im = 0; im < 4; ++im)
#pragma unroll
        for (int jn = 0; jn < 4; ++jn)
            acc[im][jn] = (f32x4_t){0.f, 0.f, 0.f, 0.f};

    const int sA_base = (wr * 64 + lrow) * 32 + kchunk;
    const int sB_base = (wc * 64 + lrow) * 32 + kchunk;

    for (int k0 = 0; k0 < K_IN; k0 += 32) {
        async_ld16(gA0 + k0, lA0);
        async_ld16(gA1 + k0, lA1);
        async_ld16(gB0 + k0, lB0);
        async_ld16(gB1 + k0, lB1);
        __syncthreads();   // drains vmcnt (global_load_lds) + barrier

        bf16x8_t af[4], bfr[4];
#pragma unroll
        for (int im = 0; im < 4; ++im)
            af[im] = *(const bf16x8_t*)(sA + sA_base + im * 16 * 32);
#pragma unroll
        for (int jn = 0; jn < 4; ++jn)
            bfr[jn] = *(const bf16x8_t*)(sB + sB_base + jn * 16 * 32);

#pragma unroll
        for (int im = 0; im < 4; ++im)
#pragma unroll
            for (int jn = 0; jn < 4; ++jn)
                acc[im][jn] = __builtin_amdgcn_mfma_f32_16x16x32_bf16(
                    af[im], bfr[jn], acc[im][jn], 0, 0, 0);

        __syncthreads();   // protect LDS before next stage
    }

    // Epilogue: C/D layout col = lane&15, row = (lane>>4)*4 + reg
    const int crow0 = m0 + wr * 64 + (lane >> 4) * 4;
    const int ccol0 = n0 + wc * 64 + lrow;
#pragma unroll
    for (int im = 0; im < 4; ++im)
#pragma unroll
        for (int jn = 0; jn < 4; ++jn)
#pragma unroll
            for (int r = 0; r < 4; ++r)
                C[(size_t)(crow0 + im * 16 + r) * N_OUT + ccol0 + jn * 16] =
                    acc[im][jn][r];
}

extern "C" void kernel_launch(void* const* d_in, const int* in_sizes, int n_in,
                              void* d_out, int out_size, void* d_ws, size_t ws_size,
                              hipStream_t stream) {
    const float* x    = (const float*)d_in[0];   // [2,2048,4096] fp32
    const float* data = (const float*)d_in[1];   // [NNZ]
    const int*   rows = (const int*)d_in[2];
    const int*   cols = (const int*)d_in[3];
    float*       out  = (float*)d_out;           // [2,2048,4096] fp32

    // workspace layout
    float*          W_f32  = (float*)d_ws;                                 // 64 MiB
    unsigned short* W_bf16 = (unsigned short*)((char*)d_ws + (64u << 20)); // 32 MiB
    unsigned short* x_bf16 = (unsigned short*)((char*)d_ws + (96u << 20)); // 32 MiB

    const int conv_blocks = (N_OUT * K_IN) / (4 * 256);  // 16384

    // 1. fused: zero W accumulator + convert x -> bf16
    zero_and_convert_x<<<conv_blocks, 256, 0, stream>>>(
        (float4*)W_f32, (const float4*)x, (ushort4*)x_bf16);

    // 2. scatter COO -> dense fp32
    scatter_coo<<<(NNZ_N + 255) / 256, 256, 0, stream>>>(data, rows, cols, W_f32, NNZ_N);

    // 3. convert W -> bf16
    convert_f32_bf16<<<conv_blocks, 256, 0, stream>>>((const float4*)W_f32, (ushort4*)W_bf16);

    // 4. y = x * W^T via bf16 MFMA GEMM
    dim3 grid(N_OUT / 128, M_ROWS / 128);  // 32 x 32
    gemm_bt<<<grid, 256, 0, stream>>>(x_bf16, W_bf16, out);
}

// Round 3
// 375.585 us; speedup vs baseline: 1.1228x; 1.0877x over previous
//
#include <hip/hip_runtime.h>
#include <stdint.h>

#define M_ROWS 4096   // BATCH*SEQ
#define N_OUT  4096   // OUT_FEATURES
#define K_IN   4096   // IN_FEATURES
#define NNZ_N  1677722

typedef __attribute__((ext_vector_type(8))) short  bf16x8_t;  // 8 bf16 in 4 VGPRs
typedef __attribute__((ext_vector_type(4))) float  f32x4_t;

// ---------- fp32 -> bf16 (RNE) ----------
__device__ __forceinline__ unsigned short f2bf(float f) {
    union { float f; uint32_t u; } v; v.f = f;
    uint32_t u = v.u;
    u += 0x7FFFu + ((u >> 16) & 1u);   // round-to-nearest-even
    return (unsigned short)(u >> 16);
}

// ---------- fused: zero W_f32 accumulator + convert x to bf16 ----------
__global__ void zero_and_convert_x(float4* __restrict__ Wz,
                                   const float4* __restrict__ x,
                                   ushort4* __restrict__ xo) {
    int i = blockIdx.x * blockDim.x + threadIdx.x;  // exact-size grid
    Wz[i] = (float4){0.f, 0.f, 0.f, 0.f};
    float4 v = x[i];
    ushort4 o;
    o.x = f2bf(v.x); o.y = f2bf(v.y); o.z = f2bf(v.z); o.w = f2bf(v.w);
    xo[i] = o;
}

__global__ void convert_f32_bf16(const float4* __restrict__ src,
                                 ushort4* __restrict__ dst) {
    int i = blockIdx.x * blockDim.x + threadIdx.x;
    float4 v = src[i];
    ushort4 o;
    o.x = f2bf(v.x); o.y = f2bf(v.y); o.z = f2bf(v.z); o.w = f2bf(v.w);
    dst[i] = o;
}

// ---------- COO scatter-add into dense W_f32 [N_OUT][K_IN] ----------
__global__ void scatter_coo(const float* __restrict__ data,
                            const int* __restrict__ rows,
                            const int* __restrict__ cols,
                            float* __restrict__ W, int nnz) {
    int i = blockIdx.x * blockDim.x + threadIdx.x;
    if (i < nnz) {
        atomicAdd(&W[(size_t)rows[i] * K_IN + cols[i]], data[i]);
    }
}

// ---------- async global->LDS helper (width 16B) ----------
__device__ __forceinline__ void async_ld16(const void* g, void* lds_wave_base) {
    __builtin_amdgcn_global_load_lds(
        (const __attribute__((address_space(1))) uint32_t*)g,
        (__attribute__((address_space(3))) uint32_t*)lds_wave_base,
        16, 0, 0);
}

// ---------- C[M][N] = A[M][K] * B[N][K]^T, bf16 inputs, fp32 out ----------
// 128x128 block tile, BK=32, 256 threads = 4 waves (2x2 of 64x64 wave tiles),
// each wave: 4x4 grid of 16x16x32 MFMAs.
//
// LDS layout XOR-swizzled (conflict-free, verified R2: SQ_LDS_BANK_CONFLICT=0).
// __launch_bounds__(256,4): cap unified VGPR+AGPR at 128/wave so 4 blocks/CU
// are resident (R2 ran at 3 blocks/CU -> 256-block tail wave, occupancy 22%).
__global__ __launch_bounds__(256, 4) void gemm_bt(const unsigned short* __restrict__ A,
                                                  const unsigned short* __restrict__ B,
                                                  float* __restrict__ C) {
    __shared__ __align__(16) unsigned short sA[128 * 32];
    __shared__ __align__(16) unsigned short sB[128 * 32];

    const int t    = threadIdx.x;
    const int wave = t >> 6;
    const int lane = t & 63;
    const int wr   = wave >> 1;       // wave row (0..1)
    const int wc   = wave & 1;        // wave col (0..1)
    const int m0   = blockIdx.y * 128;
    const int n0   = blockIdx.x * 128;

    // Staging: tile = 128 rows x 32 k-elems bf16 = 512 x 16B chunks
    //   = 2 instrs x 256 threads. LDS chunk lin = it*256 + t holds global
    //   (row = lin>>2, chunk c_src = (lin&3) ^ ((row>>1)&3)).
    const int r0    = t >> 2;                         // rows 0..63   (instr 0)
    const int r1    = 64 + (t >> 2);                  // rows 64..127 (instr 1)
    const int c_src = ((t & 3) ^ ((t >> 3) & 3)) * 8; // swizzled source chunk

    const unsigned short* gA0 = A + (size_t)(m0 + r0) * K_IN + c_src;
    const unsigned short* gA1 = A + (size_t)(m0 + r1) * K_IN + c_src;
    const unsigned short* gB0 = B + (size_t)(n0 + r0) * K_IN + c_src;
    const unsigned short* gB1 = B + (size_t)(n0 + r1) * K_IN + c_src;

    // wave-uniform LDS bases (HW adds lane*16B)
    unsigned short* lA0 = sA + wave * 512;
    unsigned short* lA1 = sA + 2048 + wave * 512;
    unsigned short* lB0 = sB + wave * 512;
    unsigned short* lB1 = sB + 2048 + wave * 512;

    const int lrow = lane & 15;           // m/n index within 16
    // swizzled k-chunk for frag reads: physical chunk = (lane>>4) ^ ((lrow>>1)&3)
    const int kchunk = ((lane >> 4) ^ ((lrow >> 1) & 3)) * 8;

    f32x4_t acc[4][4];
#pragma unroll
    for (int im = 0; im < 4; ++im)
#pragma unroll
        for (int jn = 0; jn < 4; ++jn)
            acc[im][jn] = (f32x4_t){0.f, 0.f, 0.f, 0.f};

    const int sA_base = (wr * 64 + lrow) * 32 + kchunk;
    const int sB_base = (wc * 64 + lrow) * 32 + kchunk;

    for (int k0 = 0; k0 < K_IN; k0 += 32) {
        async_ld16(gA0 + k0, lA0);
        async_ld16(gA1 + k0, lA1);
        async_ld16(gB0 + k0, lB0);
        async_ld16(gB1 + k0, lB1);
        __syncthreads();   // drains vmcnt (global_load_lds) + barrier

        bf16x8_t af[4], bfr[4];
#pragma unroll
        for (int im = 0; im < 4; ++im)
            af[im] = *(const bf16x8_t*)(sA + sA_base + im * 16 * 32);
#pragma unroll
        for (int jn = 0; jn < 4; ++jn)
            bfr[jn] = *(const bf16x8_t*)(sB + sB_base + jn * 16 * 32);

#pragma unroll
        for (int im = 0; im < 4; ++im)
#pragma unroll
            for (int jn = 0; jn < 4; ++jn)
                acc[im][jn] = __builtin_amdgcn_mfma_f32_16x16x32_bf16(
                    af[im], bfr[jn], acc[im][jn], 0, 0, 0);

        __syncthreads();   // protect LDS before next stage
    }

    // Epilogue: C/D layout col = lane&15, row = (lane>>4)*4 + reg
    const int crow0 = m0 + wr * 64 + (lane >> 4) * 4;
    const int ccol0 = n0 + wc * 64 + lrow;
#pragma unroll
    for (int im = 0; im < 4; ++im)
#pragma unroll
        for (int jn = 0; jn < 4; ++jn)
#pragma unroll
            for (int r = 0; r < 4; ++r)
                C[(size_t)(crow0 + im * 16 + r) * N_OUT + ccol0 + jn * 16] =
                    acc[im][jn][r];
}

extern "C" void kernel_launch(void* const* d_in, const int* in_sizes, int n_in,
                              void* d_out, int out_size, void* d_ws, size_t ws_size,
                              hipStream_t stream) {
    const float* x    = (const float*)d_in[0];   // [2,2048,4096] fp32
    const float* data = (const float*)d_in[1];   // [NNZ]
    const int*   rows = (const int*)d_in[2];
    const int*   cols = (const int*)d_in[3];
    float*       out  = (float*)d_out;           // [2,2048,4096] fp32

    // workspace layout
    float*          W_f32  = (float*)d_ws;                                 // 64 MiB
    unsigned short* W_bf16 = (unsigned short*)((char*)d_ws + (64u << 20)); // 32 MiB
    unsigned short* x_bf16 = (unsigned short*)((char*)d_ws + (96u << 20)); // 32 MiB

    const int conv_blocks = (N_OUT * K_IN) / (4 * 256);  // 16384

    // 1. fused: zero W accumulator + convert x -> bf16
    zero_and_convert_x<<<conv_blocks, 256, 0, stream>>>(
        (float4*)W_f32, (const float4*)x, (ushort4*)x_bf16);

    // 2. scatter COO -> dense fp32
    scatter_coo<<<(NNZ_N + 255) / 256, 256, 0, stream>>>(data, rows, cols, W_f32, NNZ_N);

    // 3. convert W -> bf16
    convert_f32_bf16<<<conv_blocks, 256, 0, stream>>>((const float4*)W_f32, (ushort4*)W_bf16);

    // 4. y = x * W^T via bf16 MFMA GEMM
    dim3 grid(N_OUT / 128, M_ROWS / 128);  // 32 x 32
    gemm_bt<<<grid, 256, 0, stream>>>(x_bf16, W_bf16, out);
}